// Round 20
// baseline (152.026 us; speedup 1.0000x reference)
//
#include <hip/hip_runtime.h>
#include <stdint.h>

#define B   256
#define IU  8      // in_units (i)
#define JC  1152   // in_channels (j)
#define NN  10     // num_units (n)
#define UU  16     // unit_size (u)
#define NU  160    // NN*UU
#define JN  11520  // JC*NN
#define WROW 1280  // NN*UU*IU, floats per j in W
#define NP  9216   // IU*JC, x row length
#define KB  72     // k-split count (16 j per slice, 2 chunks of 8)

typedef short bf16x8 __attribute__((ext_vector_type(8)));
typedef float f32x4  __attribute__((ext_vector_type(4)));

__device__ __forceinline__ short f2bf(float f) {
    union { float f; uint32_t u; } cv; cv.f = f;
    uint32_t u = cv.u;
    uint32_t r = u + 0x7fffu + ((u >> 16) & 1u);
    return (short)(r >> 16);
}
__device__ __forceinline__ float bf2f(short h) {
    union { uint32_t u; float f; } cv; cv.u = ((uint32_t)(unsigned short)h) << 16;
    return cv.f;
}
__device__ __forceinline__ uint32_t bfbits(float f) {
    union { float f; uint32_t u; } cv; cv.f = f;
    return (cv.u + 0x7fffu + ((cv.u >> 16) & 1u)) >> 16;
}
__device__ __forceinline__ uint32_t pk2(float a, float b) {
    return bfbits(a) | (bfbits(b) << 16);
}

// ---------------- pass 1 MFMA GEMM: s = x[256,9216] * (c*W)^T ------------
// grid (KB=72 k-splits of 16 j, 8 m-tiles of 32 b) = 576 blocks; 4 waves.
// Wave wv: m-frag = wv>>1 (16 b), nu-half = (wv&1)*5 tiles. LDS 24 KB.
// Slice commit: s_part[kb*8+mt][b_local(32)][nu(160)] dense.
__global__ void __launch_bounds__(256, 2)
k_gemm1(const float* __restrict__ xg, const float* __restrict__ wg,
        const float* __restrict__ cptr, float* __restrict__ s_part) {
    const int kb = blockIdx.x, mt = blockIdx.y;
    const int tid = threadIdx.x;
    const int wv = tid >> 6, lane = tid & 63;
    const int q = lane >> 4, l16 = lane & 15;
    const int b0 = mt * 32;
    const int jb0 = kb * 16;
    const int mfrag = wv >> 1;          // 0..1
    const int ntb = (wv & 1) * 5;       // 0 or 5

    __shared__ __align__(16) short As[8 * 32 * 8];   // 4 KB  [jj][bl][ii]
    __shared__ __align__(16) short Bs[8 * 160 * 8];  // 20 KB [jj][nu][ii]

    f32x4 acc[5];
    #pragma unroll
    for (int nt = 0; nt < 5; ++nt) acc[nt] = (f32x4){0.f, 0.f, 0.f, 0.f};

    for (int jc = 0; jc < 2; ++jc) {
        const int j0 = jb0 + jc * 8;
        __syncthreads();
        // stage As: x[b0+bl][ii][j0+jj] -> As[jj][bl][ii]  (512 float4s)
        #pragma unroll
        for (int p = 0; p < 2; ++p) {
            int idx = tid + 256 * p;        // 0..511
            int jq  = idx & 1;
            int row = idx >> 1;             // bl*8+ii
            int bl = row >> 3, ii = row & 7;
            const float4 xv = *reinterpret_cast<const float4*>(
                &xg[(size_t)(b0 + bl) * NP + ii * JC + j0 + jq*4]);
            int jjb = jq * 4;
            As[((jjb+0)*32 + bl)*8 + ii] = f2bf(xv.x);
            As[((jjb+1)*32 + bl)*8 + ii] = f2bf(xv.y);
            As[((jjb+2)*32 + bl)*8 + ii] = f2bf(xv.z);
            As[((jjb+3)*32 + bl)*8 + ii] = f2bf(xv.w);
        }
        // stage Bs: one W row (8 i, 32B contig) -> one ds_write_b128
        #pragma unroll
        for (int p = 0; p < 5; ++p) {
            int ridx = tid + 256 * p;       // 0..1279 = jj*160+nu
            int jj = ridx / 160;
            int nu = ridx - jj * 160;
            int j  = j0 + jj;
            const float4* wp = reinterpret_cast<const float4*>(
                &wg[(size_t)j * WROW + (size_t)nu * 8]);
            float4 f0 = wp[0], f1 = wp[1];
            float cc = cptr ? cptr[j * NN + (nu >> 4)] : (1.0f / (float)JC);
            uint4 d;
            d.x = pk2(f0.x * cc, f0.y * cc);
            d.y = pk2(f0.z * cc, f0.w * cc);
            d.z = pk2(f1.x * cc, f1.y * cc);
            d.w = pk2(f1.z * cc, f1.w * cc);
            *reinterpret_cast<uint4*>(&Bs[(size_t)ridx * 8]) = d;
        }
        __syncthreads();
        #pragma unroll
        for (int s = 0; s < 2; ++s) {
            int jj = s*4 + q;
            bf16x8 av = *reinterpret_cast<const bf16x8*>(
                &As[((jj*32 + mfrag*16 + l16) << 3)]);
            #pragma unroll
            for (int nt = 0; nt < 5; ++nt) {
                bf16x8 bv = *reinterpret_cast<const bf16x8*>(
                    &Bs[((jj*160 + (ntb + nt)*16 + l16) << 3)]);
                acc[nt] = __builtin_amdgcn_mfma_f32_16x16x32_bf16(av, bv, acc[nt], 0, 0, 0);
            }
        }
    }
    // commit: b_local = mfrag*16 + q*4 + reg, nu = (ntb+nt)*16 + l16
    float* dst = s_part + (size_t)(kb*8 + mt) * 5120;
    #pragma unroll
    for (int nt = 0; nt < 5; ++nt)
        #pragma unroll
        for (int reg = 0; reg < 4; ++reg)
            dst[(mfrag*16 + q*4 + reg) * 160 + (ntb + nt)*16 + l16] = acc[nt][reg];
}

// ---------------- fused reduce (72 slices) + squash ----------------------
// 256 blocks (one per b) x 320 threads: kq = tid/160 in {0,1} sums 36 slices,
// coalesced across t = tid%160; LDS 2-way combine; squash; write v/out.
__global__ void __launch_bounds__(320, 2)
k_reduce_s(const float* __restrict__ s_part, float* __restrict__ vdst) {
    const int b = blockIdx.x, tid = threadIdx.x;
    const int t = tid % 160, kq = tid / 160;
    const int mt = b >> 5, bl = b & 31;
    const size_t off = (size_t)mt * 5120 + bl * 160 + t;

    float s = 0.f;
    for (int r = 0; r < 36; ++r)
        s += s_part[(size_t)(kq*36 + r) * 40960 + off];

    __shared__ float red[2][160];
    __shared__ float sv[NU];
    __shared__ float fb[UU];
    red[kq][t] = s;
    __syncthreads();
    if (tid < NU) sv[tid] = red[0][tid] + red[1][tid];
    __syncthreads();
    if (tid < UU) {
        float m = 0.f;
        #pragma unroll
        for (int n = 0; n < NN; ++n) { float z = sv[n*16 + tid]; m = fmaf(z, z, m); }
        fb[tid] = sqrtf(m) / (1.f + m);
    }
    __syncthreads();
    if (tid < NU)
        vdst[(size_t)b * NU + tid] = sv[tid] * fb[tid & 15];
}

// ---------------- pass 2a: G[nu][n'] = sum_b v[b][nu] * x[b][n'] ---------
__global__ void __launch_bounds__(256, 2)
k_vxg(const float* __restrict__ vg, const float* __restrict__ xg,
      float* __restrict__ G) {
    const int np0 = blockIdx.x * 64, m0 = blockIdx.y * 32;
    const int tid = threadIdx.x;
    const int wv = tid >> 6, lane = tid & 63;
    const int q = lane >> 4, l16 = lane & 15;

    __shared__ __align__(16) short Ash[8 * 32 * 8];
    __shared__ __align__(16) short Asl[8 * 32 * 8];
    __shared__ __align__(16) short Bsh[8 * 64 * 8];
    __shared__ __align__(16) short Bsl[8 * 64 * 8];

    f32x4 acc[2];
    acc[0] = (f32x4){0.f,0.f,0.f,0.f};
    acc[1] = (f32x4){0.f,0.f,0.f,0.f};

    for (int ks = 0; ks < 4; ++ks) {
        const int b0 = ks * 64;
        __syncthreads();
        #pragma unroll
        for (int p = 0; p < 8; ++p) {
            int idx = tid + 256 * p;
            int bb = idx >> 5, ml = idx & 31;
            float vv = vg[(size_t)(b0 + bb) * NU + m0 + ml];
            short hi = f2bf(vv);
            short lo = f2bf(vv - bf2f(hi));
            int a = ((bb >> 3) * 32 + ml) * 8 + (bb & 7);
            Ash[a] = hi; Asl[a] = lo;
        }
        #pragma unroll
        for (int p = 0; p < 16; ++p) {
            int idx = tid + 256 * p;
            int bb = idx >> 6, nl = idx & 63;
            float xv = xg[(size_t)(b0 + bb) * NP + np0 + nl];
            short hi = f2bf(xv);
            short lo = f2bf(xv - bf2f(hi));
            int a = ((bb >> 3) * 64 + nl) * 8 + (bb & 7);
            Bsh[a] = hi; Bsl[a] = lo;
        }
        __syncthreads();
        #pragma unroll
        for (int s = 0; s < 2; ++s) {
            int kc = s*4 + q;
            bf16x8 bh = *reinterpret_cast<const bf16x8*>(&Bsh[((kc*64 + wv*16 + l16) << 3)]);
            bf16x8 bl = *reinterpret_cast<const bf16x8*>(&Bsl[((kc*64 + wv*16 + l16) << 3)]);
            #pragma unroll
            for (int mtl = 0; mtl < 2; ++mtl) {
                bf16x8 ah = *reinterpret_cast<const bf16x8*>(&Ash[((kc*32 + mtl*16 + l16) << 3)]);
                bf16x8 al = *reinterpret_cast<const bf16x8*>(&Asl[((kc*32 + mtl*16 + l16) << 3)]);
                acc[mtl] = __builtin_amdgcn_mfma_f32_16x16x32_bf16(ah, bh, acc[mtl], 0, 0, 0);
                acc[mtl] = __builtin_amdgcn_mfma_f32_16x16x32_bf16(ah, bl, acc[mtl], 0, 0, 0);
                acc[mtl] = __builtin_amdgcn_mfma_f32_16x16x32_bf16(al, bh, acc[mtl], 0, 0, 0);
            }
        }
    }
    #pragma unroll
    for (int mtl = 0; mtl < 2; ++mtl)
        #pragma unroll
        for (int reg = 0; reg < 4; ++reg) {
            int m  = m0 + mtl*16 + q*4 + reg;
            G[(size_t)m * NP + np0 + wv*16 + l16] = acc[mtl][reg];
        }
}

// ---------------- pass 2b: db[j,n] = sum_{u,i} W[j,n,u,i]*G[nu][i*JC+j] --
__global__ void k_wg_db(const float* __restrict__ wg, const float* __restrict__ G,
                        float* __restrict__ db) {
    const int j0 = blockIdx.x * 64, n = blockIdx.y;
    const int tid = threadIdx.x;
    const int jl = tid & 63, up = tid >> 6;
    const int j = j0 + jl;

    const float4* wp = reinterpret_cast<const float4*>(
        wg + (size_t)j * WROW + n * 128 + up * 32);
    float acc = 0.f;
    #pragma unroll
    for (int q4 = 0; q4 < 4; ++q4) {
        int u = up*4 + q4;
        const float* gp = G + (size_t)(n*16 + u) * NP + j;
        float4 w0 = wp[q4*2], w1 = wp[q4*2 + 1];
        acc = fmaf(w0.x, gp[0*JC], acc);
        acc = fmaf(w0.y, gp[1*JC], acc);
        acc = fmaf(w0.z, gp[2*JC], acc);
        acc = fmaf(w0.w, gp[3*JC], acc);
        acc = fmaf(w1.x, gp[4*JC], acc);
        acc = fmaf(w1.y, gp[5*JC], acc);
        acc = fmaf(w1.z, gp[6*JC], acc);
        acc = fmaf(w1.w, gp[7*JC], acc);
    }
    __shared__ float red[4][64];
    red[up][jl] = acc;
    __syncthreads();
    if (tid < 64)
        db[(size_t)(j0 + tid) * NN + n] =
            red[0][tid] + red[1][tid] + red[2][tid] + red[3][tid];
}

// ---- fused: blog = blog*scale0 + db/B; c = softmax_j(blog) --------------
// scale0 = 0 on the first routing update (blog is uninitialized poison).
__global__ void k_softmax_upd(float* __restrict__ blog, const float* __restrict__ db,
                              float* __restrict__ c, float scale0) {
    int n = blockIdx.x;
    int tid = threadIdx.x;        // 256
    float myv[5]; int cnt = 0;
    for (int j = tid; j < JC; j += 256) {
        float val = blog[j*NN + n] * scale0 + db[j*NN + n] * (1.f / (float)B);
        blog[j*NN + n] = val;
        myv[cnt++] = val;
    }
    __shared__ float red[256];
    float m = -1e30f;
    for (int k = 0; k < cnt; ++k) m = fmaxf(m, myv[k]);
    red[tid] = m; __syncthreads();
    for (int s = 128; s > 0; s >>= 1) {
        if (tid < s) red[tid] = fmaxf(red[tid], red[tid+s]);
        __syncthreads();
    }
    m = red[0]; __syncthreads();
    float sum = 0.f;
    for (int k = 0; k < cnt; ++k) sum += __expf(myv[k] - m);
    red[tid] = sum; __syncthreads();
    for (int s = 128; s > 0; s >>= 1) {
        if (tid < s) red[tid] += red[tid+s];
        __syncthreads();
    }
    float inv = 1.f / red[0];
    cnt = 0;
    for (int j = tid; j < JC; j += 256)
        c[j*NN + n] = __expf(myv[cnt++] - m) * inv;
}

extern "C" void kernel_launch(void* const* d_in, const int* in_sizes, int n_in,
                              void* d_out, int out_size, void* d_ws, size_t ws_size,
                              hipStream_t stream) {
    const float* x = (const float*)d_in[0];
    const float* w = (const float*)d_in[1];
    float* out = (float*)d_out;

    float* ws     = (float*)d_ws;
    float* blog   = ws;                           // 11520
    float* c      = blog + JN;                    // 11520
    float* db     = c + JN;                       // 11520
    float* v      = db + JN;                      // 40960
    float* s_part = v + (size_t)B*NU;             // 72*40960 = 2,949,120
    float* G      = s_part + (size_t)KB * 40960;  // 1,474,560
    // total ≈ 17.9 MB

    for (int t = 0; t < 3; ++t) {
        k_gemm1<<<dim3(KB, 8), 256, 0, stream>>>(x, w, (t == 0) ? nullptr : c, s_part);
        k_reduce_s<<<B, 320, 0, stream>>>(s_part, (t == 2) ? out : v);
        if (t < 2) {
            k_vxg<<<dim3(144, 5), 256, 0, stream>>>(v, x, G);
            k_wg_db<<<dim3(18, 10), 256, 0, stream>>>(w, G, db);
            k_softmax_upd<<<NN, 256, 0, stream>>>(blog, db, c, (t == 0) ? 0.f : 1.f);
        }
    }
}

// Round 21
// 147.896 us; speedup vs baseline: 1.0279x; 1.0279x over previous
//
#include <hip/hip_runtime.h>
#include <stdint.h>

#define B   256
#define IU  8      // in_units (i)
#define JC  1152   // in_channels (j)
#define NN  10     // num_units (n)
#define UU  16     // unit_size (u)
#define NU  160    // NN*UU
#define JN  11520  // JC*NN
#define WROW 1280  // NN*UU*IU, floats per j in W
#define NP  9216   // IU*JC, x row length
#define KB  72     // k-split count (16 j per slice, 2 chunks of 8)

typedef short bf16x8 __attribute__((ext_vector_type(8)));
typedef float f32x4  __attribute__((ext_vector_type(4)));

__device__ __forceinline__ short f2bf(float f) {
    union { float f; uint32_t u; } cv; cv.f = f;
    uint32_t u = cv.u;
    uint32_t r = u + 0x7fffu + ((u >> 16) & 1u);
    return (short)(r >> 16);
}
__device__ __forceinline__ float bf2f(short h) {
    union { uint32_t u; float f; } cv; cv.u = ((uint32_t)(unsigned short)h) << 16;
    return cv.f;
}
__device__ __forceinline__ uint32_t bfbits(float f) {
    union { float f; uint32_t u; } cv; cv.f = f;
    return (cv.u + 0x7fffu + ((cv.u >> 16) & 1u)) >> 16;
}
__device__ __forceinline__ uint32_t pk2(float a, float b) {
    return bfbits(a) | (bfbits(b) << 16);
}

// ---------------- pass 1 MFMA GEMM: s = x[256,9216] * (c*W)^T ------------
// grid (KB=72 k-splits of 16 j, 8 m-tiles of 32 b) = 576 blocks; 4 waves.
// c-normalization fused: cc = eblog[j,n] * (1/expsum[n]); eblog==nullptr on
// iter 0 -> cc = 1/JC exactly (softmax of zeros).
__global__ void __launch_bounds__(256, 2)
k_gemm1(const float* __restrict__ xg, const float* __restrict__ wg,
        const float* __restrict__ eblog, const float* __restrict__ expsum,
        float* __restrict__ s_part) {
    const int kb = blockIdx.x, mt = blockIdx.y;
    const int tid = threadIdx.x;
    const int wv = tid >> 6, lane = tid & 63;
    const int q = lane >> 4, l16 = lane & 15;
    const int b0 = mt * 32;
    const int jb0 = kb * 16;
    const int mfrag = wv >> 1;          // 0..1
    const int ntb = (wv & 1) * 5;       // 0 or 5

    __shared__ __align__(16) short As[8 * 32 * 8];   // 4 KB  [jj][bl][ii]
    __shared__ __align__(16) short Bs[8 * 160 * 8];  // 20 KB [jj][nu][ii]
    __shared__ float inv_s[NN];

    if (eblog && tid < NN) inv_s[tid] = 1.f / expsum[tid];

    f32x4 acc[5];
    #pragma unroll
    for (int nt = 0; nt < 5; ++nt) acc[nt] = (f32x4){0.f, 0.f, 0.f, 0.f};

    for (int jc = 0; jc < 2; ++jc) {
        const int j0 = jb0 + jc * 8;
        __syncthreads();                // also publishes inv_s on first pass
        // stage As: x[b0+bl][ii][j0+jj] -> As[jj][bl][ii]  (512 float4s)
        #pragma unroll
        for (int p = 0; p < 2; ++p) {
            int idx = tid + 256 * p;        // 0..511
            int jq  = idx & 1;
            int row = idx >> 1;             // bl*8+ii
            int bl = row >> 3, ii = row & 7;
            const float4 xv = *reinterpret_cast<const float4*>(
                &xg[(size_t)(b0 + bl) * NP + ii * JC + j0 + jq*4]);
            int jjb = jq * 4;
            As[((jjb+0)*32 + bl)*8 + ii] = f2bf(xv.x);
            As[((jjb+1)*32 + bl)*8 + ii] = f2bf(xv.y);
            As[((jjb+2)*32 + bl)*8 + ii] = f2bf(xv.z);
            As[((jjb+3)*32 + bl)*8 + ii] = f2bf(xv.w);
        }
        // stage Bs: one W row (8 i, 32B contig) -> one ds_write_b128
        #pragma unroll
        for (int p = 0; p < 5; ++p) {
            int ridx = tid + 256 * p;       // 0..1279 = jj*160+nu
            int jj = ridx / 160;
            int nu = ridx - jj * 160;
            int j  = j0 + jj;
            const float4* wp = reinterpret_cast<const float4*>(
                &wg[(size_t)j * WROW + (size_t)nu * 8]);
            float4 f0 = wp[0], f1 = wp[1];
            int nn = nu >> 4;
            float cc = eblog ? eblog[j * NN + nn] * inv_s[nn]
                             : (1.0f / (float)JC);
            uint4 d;
            d.x = pk2(f0.x * cc, f0.y * cc);
            d.y = pk2(f0.z * cc, f0.w * cc);
            d.z = pk2(f1.x * cc, f1.y * cc);
            d.w = pk2(f1.z * cc, f1.w * cc);
            *reinterpret_cast<uint4*>(&Bs[(size_t)ridx * 8]) = d;
        }
        __syncthreads();
        #pragma unroll
        for (int s = 0; s < 2; ++s) {
            int jj = s*4 + q;
            bf16x8 av = *reinterpret_cast<const bf16x8*>(
                &As[((jj*32 + mfrag*16 + l16) << 3)]);
            #pragma unroll
            for (int nt = 0; nt < 5; ++nt) {
                bf16x8 bv = *reinterpret_cast<const bf16x8*>(
                    &Bs[((jj*160 + (ntb + nt)*16 + l16) << 3)]);
                acc[nt] = __builtin_amdgcn_mfma_f32_16x16x32_bf16(av, bv, acc[nt], 0, 0, 0);
            }
        }
    }
    // commit: b_local = mfrag*16 + q*4 + reg, nu = (ntb+nt)*16 + l16
    float* dst = s_part + (size_t)(kb*8 + mt) * 5120;
    #pragma unroll
    for (int nt = 0; nt < 5; ++nt)
        #pragma unroll
        for (int reg = 0; reg < 4; ++reg)
            dst[(mfrag*16 + q*4 + reg) * 160 + (ntb + nt)*16 + l16] = acc[nt][reg];
}

// ---------------- fused reduce (72 slices) + squash ----------------------
__global__ void __launch_bounds__(320, 2)
k_reduce_s(const float* __restrict__ s_part, float* __restrict__ vdst) {
    const int b = blockIdx.x, tid = threadIdx.x;
    const int t = tid % 160, kq = tid / 160;
    const int mt = b >> 5, bl = b & 31;
    const size_t off = (size_t)mt * 5120 + bl * 160 + t;

    float s = 0.f;
    for (int r = 0; r < 36; ++r)
        s += s_part[(size_t)(kq*36 + r) * 40960 + off];

    __shared__ float red[2][160];
    __shared__ float sv[NU];
    __shared__ float fb[UU];
    red[kq][t] = s;
    __syncthreads();
    if (tid < NU) sv[tid] = red[0][tid] + red[1][tid];
    __syncthreads();
    if (tid < UU) {
        float m = 0.f;
        #pragma unroll
        for (int n = 0; n < NN; ++n) { float z = sv[n*16 + tid]; m = fmaf(z, z, m); }
        fb[tid] = sqrtf(m) / (1.f + m);
    }
    __syncthreads();
    if (tid < NU)
        vdst[(size_t)b * NU + tid] = sv[tid] * fb[tid & 15];
}

// ---------------- pass 2a: G[nu][n'] = sum_b v[b][nu] * x[b][n'] ---------
// Block (0,0) also zeroes expsum for the following k_wg_db (stream-ordered).
__global__ void __launch_bounds__(256, 2)
k_vxg(const float* __restrict__ vg, const float* __restrict__ xg,
      float* __restrict__ G, float* __restrict__ expsum) {
    const int np0 = blockIdx.x * 64, m0 = blockIdx.y * 32;
    const int tid = threadIdx.x;
    const int wv = tid >> 6, lane = tid & 63;
    const int q = lane >> 4, l16 = lane & 15;

    if (blockIdx.x == 0 && blockIdx.y == 0 && tid < NN) expsum[tid] = 0.f;

    __shared__ __align__(16) short Ash[8 * 32 * 8];
    __shared__ __align__(16) short Asl[8 * 32 * 8];
    __shared__ __align__(16) short Bsh[8 * 64 * 8];
    __shared__ __align__(16) short Bsl[8 * 64 * 8];

    f32x4 acc[2];
    acc[0] = (f32x4){0.f,0.f,0.f,0.f};
    acc[1] = (f32x4){0.f,0.f,0.f,0.f};

    for (int ks = 0; ks < 4; ++ks) {
        const int b0 = ks * 64;
        __syncthreads();
        #pragma unroll
        for (int p = 0; p < 8; ++p) {
            int idx = tid + 256 * p;
            int bb = idx >> 5, ml = idx & 31;
            float vv = vg[(size_t)(b0 + bb) * NU + m0 + ml];
            short hi = f2bf(vv);
            short lo = f2bf(vv - bf2f(hi));
            int a = ((bb >> 3) * 32 + ml) * 8 + (bb & 7);
            Ash[a] = hi; Asl[a] = lo;
        }
        #pragma unroll
        for (int p = 0; p < 16; ++p) {
            int idx = tid + 256 * p;
            int bb = idx >> 6, nl = idx & 63;
            float xv = xg[(size_t)(b0 + bb) * NP + np0 + nl];
            short hi = f2bf(xv);
            short lo = f2bf(xv - bf2f(hi));
            int a = ((bb >> 3) * 64 + nl) * 8 + (bb & 7);
            Bsh[a] = hi; Bsl[a] = lo;
        }
        __syncthreads();
        #pragma unroll
        for (int s = 0; s < 2; ++s) {
            int kc = s*4 + q;
            bf16x8 bh = *reinterpret_cast<const bf16x8*>(&Bsh[((kc*64 + wv*16 + l16) << 3)]);
            bf16x8 bl = *reinterpret_cast<const bf16x8*>(&Bsl[((kc*64 + wv*16 + l16) << 3)]);
            #pragma unroll
            for (int mtl = 0; mtl < 2; ++mtl) {
                bf16x8 ah = *reinterpret_cast<const bf16x8*>(&Ash[((kc*32 + mtl*16 + l16) << 3)]);
                bf16x8 al = *reinterpret_cast<const bf16x8*>(&Asl[((kc*32 + mtl*16 + l16) << 3)]);
                acc[mtl] = __builtin_amdgcn_mfma_f32_16x16x32_bf16(ah, bh, acc[mtl], 0, 0, 0);
                acc[mtl] = __builtin_amdgcn_mfma_f32_16x16x32_bf16(ah, bl, acc[mtl], 0, 0, 0);
                acc[mtl] = __builtin_amdgcn_mfma_f32_16x16x32_bf16(al, bh, acc[mtl], 0, 0, 0);
            }
        }
    }
    #pragma unroll
    for (int mtl = 0; mtl < 2; ++mtl)
        #pragma unroll
        for (int reg = 0; reg < 4; ++reg) {
            int m  = m0 + mtl*16 + q*4 + reg;
            G[(size_t)m * NP + np0 + wv*16 + l16] = acc[mtl][reg];
        }
}

// ---- pass 2b + routing update: db -> blog, eblog=exp(blog), expsum ------
// grid (18 j-tiles of 64, 10 n), block 256. One atomicAdd per block.
// No max-subtraction needed: |blog| <= ~2 here, exp is safe; softmax value
// is mathematically identical (shift-invariance).
__global__ void k_wg_db(const float* __restrict__ wg, const float* __restrict__ G,
                        float* __restrict__ blog, float* __restrict__ eblog,
                        float* __restrict__ expsum, int t0) {
    const int j0 = blockIdx.x * 64, n = blockIdx.y;
    const int tid = threadIdx.x;
    const int jl = tid & 63, up = tid >> 6;
    const int j = j0 + jl;

    const float4* wp = reinterpret_cast<const float4*>(
        wg + (size_t)j * WROW + n * 128 + up * 32);
    float acc = 0.f;
    #pragma unroll
    for (int q4 = 0; q4 < 4; ++q4) {
        int u = up*4 + q4;
        const float* gp = G + (size_t)(n*16 + u) * NP + j;
        float4 w0 = wp[q4*2], w1 = wp[q4*2 + 1];
        acc = fmaf(w0.x, gp[0*JC], acc);
        acc = fmaf(w0.y, gp[1*JC], acc);
        acc = fmaf(w0.z, gp[2*JC], acc);
        acc = fmaf(w0.w, gp[3*JC], acc);
        acc = fmaf(w1.x, gp[4*JC], acc);
        acc = fmaf(w1.y, gp[5*JC], acc);
        acc = fmaf(w1.z, gp[6*JC], acc);
        acc = fmaf(w1.w, gp[7*JC], acc);
    }
    __shared__ float red[4][64];
    red[up][jl] = acc;
    __syncthreads();
    if (tid < 64) {   // exactly one wave
        int jj = j0 + tid;
        float d = (red[0][tid] + red[1][tid] + red[2][tid] + red[3][tid])
                  * (1.f / (float)B);
        float nb = t0 ? d : (blog[jj*NN + n] + d);
        blog[jj*NN + n] = nb;
        float e = __expf(nb);
        eblog[jj*NN + n] = e;
        float s = e;
        s += __shfl_xor(s, 1);  s += __shfl_xor(s, 2);
        s += __shfl_xor(s, 4);  s += __shfl_xor(s, 8);
        s += __shfl_xor(s, 16); s += __shfl_xor(s, 32);
        if (tid == 0) atomicAdd(&expsum[n], s);
    }
}

extern "C" void kernel_launch(void* const* d_in, const int* in_sizes, int n_in,
                              void* d_out, int out_size, void* d_ws, size_t ws_size,
                              hipStream_t stream) {
    const float* x = (const float*)d_in[0];
    const float* w = (const float*)d_in[1];
    float* out = (float*)d_out;

    float* ws     = (float*)d_ws;
    float* blog   = ws;                           // 11520
    float* eblog  = blog + JN;                    // 11520
    float* expsum = eblog + JN;                   // 16 (padded)
    float* v      = expsum + 16;                  // 40960
    float* s_part = v + (size_t)B*NU;             // 72*40960 = 2,949,120
    float* G      = s_part + (size_t)KB * 40960;  // 1,474,560
    // total ≈ 17.9 MB

    for (int t = 0; t < 3; ++t) {
        k_gemm1<<<dim3(KB, 8), 256, 0, stream>>>(
            x, w, (t == 0) ? nullptr : eblog, expsum, s_part);
        k_reduce_s<<<B, 320, 0, stream>>>(s_part, (t == 2) ? out : v);
        if (t < 2) {
            k_vxg<<<dim3(144, 5), 256, 0, stream>>>(v, x, G, expsum);
            k_wg_db<<<dim3(18, 10), 256, 0, stream>>>(w, G, blog, eblog, expsum,
                                                      (t == 0) ? 1 : 0);
        }
    }
}